// Round 1
// baseline (710.487 us; speedup 1.0000x reference)
//
#include <hip/hip_runtime.h>

// Sliding-window bandwidth-weighted regression moments.
// B=4, H=720, W=1280, C=3, win=11 (R=5), bandwidth=0.5 -> inv_bw2=4.
// Outputs (concatenated): x/wsum, xx/wsum, xy/wsum, y/wsum, each [B,H,W,C] fp32.
//
// Strategy: VALU-bound kernel (~24 ops/tap * 121 taps/px). Each thread computes
// a KX=4 horizontal strip so each LDS neighbor load feeds up to 4 taps
// (14 loads/row instead of 44). SoA LDS planes with odd row stride (75) give
// conflict-free (2-way) banked access. Boundary mask folded into the exp2 bias.

#define HH   720
#define WW   1280
#define BB   4
#define RAD  5
#define TX   64      // tile width  (16 threads x KX=4)
#define TY   16      // tile height (16 threads)
#define KX   4
#define LW   74      // tile cols incl. halo
#define LH   26      // tile rows incl. halo
#define LSTR 75      // LDS row stride (odd mod 32 -> perfect bank spread)
#define PLANE (LSTR * LH)

__global__ __launch_bounds__(256, 3)
void regression_kernel(const float* __restrict__ rnd,
                       const float* __restrict__ tgt,
                       float* __restrict__ out)
{
    __shared__ float lds[6 * PLANE];   // 46.8 KB
    float* __restrict__ pt0 = lds;
    float* __restrict__ pt1 = lds + PLANE;
    float* __restrict__ pt2 = lds + 2 * PLANE;
    float* __restrict__ pr0 = lds + 3 * PLANE;
    float* __restrict__ pr1 = lds + 4 * PLANE;
    float* __restrict__ pr2 = lds + 5 * PLANE;

    const int tx = threadIdx.x;        // 0..15
    const int ty = threadIdx.y;        // 0..15
    const int tid = ty * 16 + tx;
    const int X0 = blockIdx.x * TX;
    const int Y0 = blockIdx.y * TY;
    const int b  = blockIdx.z;

    // ---- stage tile (74x26 px, zero for OOB) into 6 SoA planes ----
    for (int i = tid; i < LW * LH; i += 256) {
        int ly = i / LW;
        int lx = i - ly * LW;
        int gy = Y0 + ly - RAD;
        int gx = X0 + lx - RAD;
        float t0 = 0.f, t1 = 0.f, t2 = 0.f, r0 = 0.f, r1 = 0.f, r2 = 0.f;
        if ((unsigned)gy < (unsigned)HH && (unsigned)gx < (unsigned)WW) {
            int off = ((b * HH + gy) * WW + gx) * 3;
            t0 = tgt[off + 0]; t1 = tgt[off + 1]; t2 = tgt[off + 2];
            r0 = rnd[off + 0]; r1 = rnd[off + 1]; r2 = rnd[off + 2];
        }
        int s = ly * LSTR + lx;
        pt0[s] = t0; pt1[s] = t1; pt2[s] = t2;
        pr0[s] = r0; pr1[s] = r1; pr2[s] = r2;
    }
    __syncthreads();

    // ---- center guide colors for the 4-px strip ----
    float tp0[KX], tp1[KX], tp2[KX];
    {
        int s = (ty + RAD) * LSTR + tx * KX + RAD;
        #pragma unroll
        for (int k = 0; k < KX; ++k) {
            tp0[k] = pt0[s + k]; tp1[k] = pt1[s + k]; tp2[k] = pt2[s + k];
        }
    }

    float sx0[KX] = {}, sx1[KX] = {}, sx2[KX] = {};
    float sxx0[KX] = {}, sxx1[KX] = {}, sxx2[KX] = {};
    float sxy0[KX] = {}, sxy1[KX] = {}, sxy2[KX] = {};
    float sy0[KX] = {}, sy1[KX] = {}, sy2[KX] = {};
    float sw[KX] = {};

    const int xbase = X0 + tx * KX - RAD;   // global x of j=0
    const int ybase = Y0 + ty - RAD;        // global y of dy=0
    const float NEG = -1e30f;
    const float CC  = -5.770780163555852f;  // -(4/bw^2) * log2(e)

    #pragma unroll 1
    for (int dy = 0; dy < 11; ++dy) {
        const float rowbias = ((unsigned)(ybase + dy) < (unsigned)HH) ? 0.f : NEG;
        const int rbase = (ty + dy) * LSTR + tx * KX;
        #pragma unroll
        for (int j = 0; j < 14; ++j) {
            const int s = rbase + j;
            const float t0 = pt0[s], t1 = pt1[s], t2 = pt2[s];
            const float r0 = pr0[s], r1 = pr1[s], r2 = pr2[s];
            const float bias = ((unsigned)(xbase + j) < (unsigned)WW) ? rowbias : NEG;
            #pragma unroll
            for (int k = 0; k < KX; ++k) {
                if (j >= k && j <= k + 10) {   // compile-time after unroll
                    float d0 = tp0[k] - t0;
                    float d1 = tp1[k] - t1;
                    float d2 = tp2[k] - t2;
                    float d  = d0 * d0;
                    d = fmaf(d1, d1, d);
                    d = fmaf(d2, d2, d);
                    float w = exp2f(fmaf(d, CC, bias));  // masked taps -> w = 0
                    float wt0 = w * t0, wt1 = w * t1, wt2 = w * t2;
                    sx0[k] += wt0;  sx1[k] += wt1;  sx2[k] += wt2;
                    sxx0[k] = fmaf(wt0, t0, sxx0[k]);
                    sxx1[k] = fmaf(wt1, t1, sxx1[k]);
                    sxx2[k] = fmaf(wt2, t2, sxx2[k]);
                    sxy0[k] = fmaf(wt0, r0, sxy0[k]);
                    sxy1[k] = fmaf(wt1, r1, sxy1[k]);
                    sxy2[k] = fmaf(wt2, r2, sxy2[k]);
                    sy0[k]  = fmaf(w, r0, sy0[k]);
                    sy1[k]  = fmaf(w, r1, sy1[k]);
                    sy2[k]  = fmaf(w, r2, sy2[k]);
                    sw[k]  += w;
                }
            }
        }
    }

    // ---- epilogue: normalize and write 4 chunks, 3x float4 each ----
    const int CH   = BB * HH * WW * 3;     // 11,059,200
    const int gy   = Y0 + ty;
    const int base = ((b * HH + gy) * WW + X0 + tx * KX) * 3;  // 16B-aligned

    float inv[KX];
    #pragma unroll
    for (int k = 0; k < KX; ++k) inv[k] = 1.0f / sw[k];

#define STORE_CHUNK(a0, a1, a2, cidx)                                         \
    {                                                                         \
        float4* p = (float4*)(out + (cidx) * CH + base);                      \
        p[0] = make_float4(a0[0]*inv[0], a1[0]*inv[0], a2[0]*inv[0],          \
                           a0[1]*inv[1]);                                     \
        p[1] = make_float4(a1[1]*inv[1], a2[1]*inv[1], a0[2]*inv[2],          \
                           a1[2]*inv[2]);                                     \
        p[2] = make_float4(a2[2]*inv[2], a0[3]*inv[3], a1[3]*inv[3],          \
                           a2[3]*inv[3]);                                     \
    }

    STORE_CHUNK(sx0,  sx1,  sx2,  0)
    STORE_CHUNK(sxx0, sxx1, sxx2, 1)
    STORE_CHUNK(sxy0, sxy1, sxy2, 2)
    STORE_CHUNK(sy0,  sy1,  sy2,  3)
#undef STORE_CHUNK
}

extern "C" void kernel_launch(void* const* d_in, const int* in_sizes, int n_in,
                              void* d_out, int out_size, void* d_ws, size_t ws_size,
                              hipStream_t stream) {
    const float* rnd = (const float*)d_in[0];   // "rand"
    const float* tgt = (const float*)d_in[1];   // "target"
    float* out = (float*)d_out;

    dim3 grid(WW / TX, HH / TY, BB);   // 20 x 45 x 4 = 3600 blocks, exact tiling
    dim3 block(16, 16);
    regression_kernel<<<grid, block, 0, stream>>>(rnd, tgt, out);
}

// Round 3
// 686.306 us; speedup vs baseline: 1.0352x; 1.0352x over previous
//
#include <hip/hip_runtime.h>

// Sliding-window bandwidth-weighted regression moments.
// B=4, H=720, W=1280, C=3, win=11 (R=5), bandwidth=0.5 -> inv_bw2=4.
// Outputs (concatenated): x/wsum, xx/wsum, xy/wsum, y/wsum, each [B,H,W,C] fp32.
//
// R2 -> R3: same algorithm; epilogue hygiene fixes after R2 core dump:
//  - LDS array explicitly 16B-aligned (float4 DS ops)
//  - plane pointers NOT __restrict__ (epilogue re-writes the same storage
//    through a different pointer -> restrict UB in R2)
//  - all float4 LDS addressing in float4 units from the array base.

#define HH   720
#define WW   1280
#define BB   4
#define RAD  5
#define TX   64      // tile width  (16 threads x KX=4)
#define TY   16      // tile height (16 threads)
#define KX   4
#define LW   74      // tile cols incl. halo
#define LH   26      // tile rows incl. halo
#define LSTR 75      // LDS row stride (odd mod 32 -> perfect bank spread)
#define PLANE (LSTR * LH)          // 1950 floats
#define LDS_FLOATS 12288           // max(6*PLANE=11700, 4*3072 epilogue) -> 48KB

__global__ __launch_bounds__(256, 3)
void regression_kernel(const float* __restrict__ rnd,
                       const float* __restrict__ tgt,
                       float* __restrict__ out)
{
    __shared__ __align__(16) float lds[LDS_FLOATS];   // 48 KB -> 3 blocks/CU
    float* pt0 = lds;
    float* pt1 = lds + PLANE;
    float* pt2 = lds + 2 * PLANE;
    float* pr0 = lds + 3 * PLANE;
    float* pr1 = lds + 4 * PLANE;
    float* pr2 = lds + 5 * PLANE;

    const int tx = threadIdx.x;        // 0..15
    const int ty = threadIdx.y;        // 0..15
    const int tid = ty * 16 + tx;
    const int X0 = blockIdx.x * TX;
    const int Y0 = blockIdx.y * TY;
    const int b  = blockIdx.z;

    // ---- stage tile (74x26 px, zero for OOB) into 6 SoA planes ----
    for (int i = tid; i < LW * LH; i += 256) {
        int ly = i / LW;
        int lx = i - ly * LW;
        int gy = Y0 + ly - RAD;
        int gx = X0 + lx - RAD;
        float t0 = 0.f, t1 = 0.f, t2 = 0.f, r0 = 0.f, r1 = 0.f, r2 = 0.f;
        if ((unsigned)gy < (unsigned)HH && (unsigned)gx < (unsigned)WW) {
            int off = ((b * HH + gy) * WW + gx) * 3;
            t0 = tgt[off + 0]; t1 = tgt[off + 1]; t2 = tgt[off + 2];
            r0 = rnd[off + 0]; r1 = rnd[off + 1]; r2 = rnd[off + 2];
        }
        int s = ly * LSTR + lx;
        pt0[s] = t0; pt1[s] = t1; pt2[s] = t2;
        pr0[s] = r0; pr1[s] = r1; pr2[s] = r2;
    }
    __syncthreads();

    // ---- center guide colors for the 4-px strip ----
    float tp0[KX], tp1[KX], tp2[KX];
    {
        int s = (ty + RAD) * LSTR + tx * KX + RAD;
        #pragma unroll
        for (int k = 0; k < KX; ++k) {
            tp0[k] = pt0[s + k]; tp1[k] = pt1[s + k]; tp2[k] = pt2[s + k];
        }
    }

    float sx0[KX] = {}, sx1[KX] = {}, sx2[KX] = {};
    float sxx0[KX] = {}, sxx1[KX] = {}, sxx2[KX] = {};
    float sxy0[KX] = {}, sxy1[KX] = {}, sxy2[KX] = {};
    float sy0[KX] = {}, sy1[KX] = {}, sy2[KX] = {};
    float sw[KX] = {};

    const int xbase = X0 + tx * KX - RAD;   // global x of j=0
    const int ybase = Y0 + ty - RAD;        // global y of dy=0
    const float NEG = -1e30f;
    const float CC  = -5.770780163555852f;  // -(4/bw^2) * log2(e)

    #pragma unroll 1
    for (int dy = 0; dy < 11; ++dy) {
        const float rowbias = ((unsigned)(ybase + dy) < (unsigned)HH) ? 0.f : NEG;
        const int rbase = (ty + dy) * LSTR + tx * KX;
        #pragma unroll
        for (int j = 0; j < 14; ++j) {
            const int s = rbase + j;
            const float t0 = pt0[s], t1 = pt1[s], t2 = pt2[s];
            const float r0 = pr0[s], r1 = pr1[s], r2 = pr2[s];
            const float bias = ((unsigned)(xbase + j) < (unsigned)WW) ? rowbias : NEG;
            #pragma unroll
            for (int k = 0; k < KX; ++k) {
                if (j >= k && j <= k + 10) {   // compile-time after unroll
                    float d0 = tp0[k] - t0;
                    float d1 = tp1[k] - t1;
                    float d2 = tp2[k] - t2;
                    float d  = d0 * d0;
                    d = fmaf(d1, d1, d);
                    d = fmaf(d2, d2, d);
                    float w = exp2f(fmaf(d, CC, bias));  // masked taps -> w = 0
                    float wt0 = w * t0, wt1 = w * t1, wt2 = w * t2;
                    sx0[k] += wt0;  sx1[k] += wt1;  sx2[k] += wt2;
                    sxx0[k] = fmaf(wt0, t0, sxx0[k]);
                    sxx1[k] = fmaf(wt1, t1, sxx1[k]);
                    sxx2[k] = fmaf(wt2, t2, sxx2[k]);
                    sxy0[k] = fmaf(wt0, r0, sxy0[k]);
                    sxy1[k] = fmaf(wt1, r1, sxy1[k]);
                    sxy2[k] = fmaf(wt2, r2, sxy2[k]);
                    sy0[k]  = fmaf(w, r0, sy0[k]);
                    sy1[k]  = fmaf(w, r1, sy1[k]);
                    sy2[k]  = fmaf(w, r2, sy2[k]);
                    sw[k]  += w;
                }
            }
        }
    }

    float inv[KX];
    #pragma unroll
    for (int k = 0; k < KX; ++k) inv[k] = 1.0f / sw[k];

    // ---- epilogue: stage normalized results in LDS (tile order), then
    //      cooperative lane-contiguous float4 stores ----
    __syncthreads();   // everyone done reading the planes

    float4* l4 = (float4*)lds;           // 3072 float4; chunk c at l4[c*768]
    {
        // within chunk: row (ty) major, 48 float4 per row, thread owns 3
        const int b4 = ty * 48 + tx * 3;
#define STAGE_CHUNK(a0, a1, a2, cidx)                                          \
        {                                                                      \
            float4* p = l4 + (cidx) * 768 + b4;                                \
            p[0] = make_float4(a0[0]*inv[0], a1[0]*inv[0], a2[0]*inv[0],       \
                               a0[1]*inv[1]);                                  \
            p[1] = make_float4(a1[1]*inv[1], a2[1]*inv[1], a0[2]*inv[2],       \
                               a1[2]*inv[2]);                                  \
            p[2] = make_float4(a2[2]*inv[2], a0[3]*inv[3], a1[3]*inv[3],       \
                               a2[3]*inv[3]);                                  \
        }
        STAGE_CHUNK(sx0,  sx1,  sx2,  0)
        STAGE_CHUNK(sxx0, sxx1, sxx2, 1)
        STAGE_CHUNK(sxy0, sxy1, sxy2, 2)
        STAGE_CHUNK(sy0,  sy1,  sy2,  3)
#undef STAGE_CHUNK
    }
    __syncthreads();

    const int CH = BB * HH * WW * 3;     // 11,059,200 floats per chunk
    // 3 distinct within-chunk float4 indices per thread: r = m*256 + tid
    int rr[3], cc4[3];
    #pragma unroll
    for (int m = 0; m < 3; ++m) {
        int r = m * 256 + tid;           // 0..767 (48 float4 per tile row)
        rr[m]  = r / 48;                 // tile row 0..15
        cc4[m] = r - rr[m] * 48;         // float4 col within row
    }
    #pragma unroll
    for (int i = 0; i < 12; ++i) {
        const int c = i / 3;             // chunk
        const int m = i - c * 3;
        float4 v = l4[c * 768 + m * 256 + tid];
        const int gaddr = c * CH + ((b * HH + Y0 + rr[m]) * WW + X0) * 3 + cc4[m] * 4;
        *(float4*)(out + gaddr) = v;     // consecutive lanes -> consecutive 16B
    }
}

extern "C" void kernel_launch(void* const* d_in, const int* in_sizes, int n_in,
                              void* d_out, int out_size, void* d_ws, size_t ws_size,
                              hipStream_t stream) {
    const float* rnd = (const float*)d_in[0];   // "rand"
    const float* tgt = (const float*)d_in[1];   // "target"
    float* out = (float*)d_out;

    dim3 grid(WW / TX, HH / TY, BB);   // 20 x 45 x 4 = 3600 blocks, exact tiling
    dim3 block(16, 16);
    regression_kernel<<<grid, block, 0, stream>>>(rnd, tgt, out);
}